// Round 1
// baseline (796.310 us; speedup 1.0000x reference)
//
#include <hip/hip_runtime.h>

typedef _Float16 half8 __attribute__((ext_vector_type(8)));
typedef _Float16 half4v __attribute__((ext_vector_type(4)));
typedef float f32x4 __attribute__((ext_vector_type(4)));

constexpr int NB = 2048;        // windows (batch)
constexpr int LLEN = 49;        // window length
constexpr int CDIM = 384;       // channels
constexpr int NH = 12;          // heads
constexpr int HD = 32;          // head dim
constexpr int MM = NB * LLEN;   // 100352 rows
constexpr float SCALE = 0.17677669529663687f;  // 1/sqrt(32)

// ---------------- convert kernels ----------------

__global__ __launch_bounds__(256) void convert_x(const float* __restrict__ x,
                                                 _Float16* __restrict__ o, int n) {
    int i = (blockIdx.x * 256 + threadIdx.x) * 4;
    if (i < n) {
        float4 v = *(const float4*)(x + i);
        half4v h = { (_Float16)v.x, (_Float16)v.y, (_Float16)v.z, (_Float16)v.w };
        *(half4v*)(o + i) = h;
    }
}

// transpose + convert qkv_w [384,1152] -> [1152,384] and proj_w [384,384] -> [384,384]^T
__global__ __launch_bounds__(256) void convert_w(const float* __restrict__ qkv_w,
                                                 const float* __restrict__ proj_w,
                                                 _Float16* __restrict__ qkvT,
                                                 _Float16* __restrict__ projT) {
    int i = blockIdx.x * 256 + threadIdx.x;
    if (i < 1152 * 384) {
        int n = i / 384, kk = i % 384;
        qkvT[i] = (_Float16)qkv_w[kk * 1152 + n];
    } else {
        int j = i - 1152 * 384;
        if (j < 384 * 384) {
            int n = j / 384, kk = j % 384;
            projT[j] = (_Float16)proj_w[kk * 384 + n];
        }
    }
}

// ---------------- QKV GEMM: [100352,384] x [384,1152] ----------------
// A [M,K] f16 row-major, Bt [N,K] f16 row-major. 128x128 tile, BK=64, 256 thr.

#define SA 72   // LDS row stride in halves (64 + 8 pad, 144B: 16B-aligned, 2-way-free)

__global__ __launch_bounds__(256) void gemm_qkv(const _Float16* __restrict__ A,
                                                const _Float16* __restrict__ Bt,
                                                const float* __restrict__ qkv_b,
                                                _Float16* __restrict__ qo,
                                                _Float16* __restrict__ ko,
                                                _Float16* __restrict__ vo) {
    __shared__ _Float16 As[128 * SA];
    __shared__ _Float16 Bs[128 * SA];
    const int K = 384;
    const int tn = blockIdx.x, tm = blockIdx.y;
    const int t = threadIdx.x;
    const int wave = t >> 6, lane = t & 63;
    const int wm = (wave & 1) * 64, wn = (wave >> 1) * 64;
    const int quad = lane >> 4, l16 = lane & 15;

    f32x4 acc[4][4] = {};

    const _Float16* Abase = A + (size_t)(tm * 128) * K;
    const _Float16* Bbase = Bt + (size_t)(tn * 128) * K;

    for (int k0 = 0; k0 < K; k0 += 64) {
        __syncthreads();
#pragma unroll
        for (int i = 0; i < 4; i++) {
            int c = t + 256 * i;          // 1024 chunks of 8 halves
            int row = c >> 3, cc = (c & 7) * 8;
            uint4 av = *(const uint4*)(Abase + (size_t)row * K + k0 + cc);
            *(uint4*)(&As[row * SA + cc]) = av;
            uint4 bv = *(const uint4*)(Bbase + (size_t)row * K + k0 + cc);
            *(uint4*)(&Bs[row * SA + cc]) = bv;
        }
        __syncthreads();
#pragma unroll
        for (int ks = 0; ks < 2; ks++) {
            half8 af[4], bfv[4];
#pragma unroll
            for (int i = 0; i < 4; i++)
                af[i] = *(const half8*)(&As[(wm + i * 16 + l16) * SA + ks * 32 + quad * 8]);
#pragma unroll
            for (int j = 0; j < 4; j++)
                bfv[j] = *(const half8*)(&Bs[(wn + j * 16 + l16) * SA + ks * 32 + quad * 8]);
#pragma unroll
            for (int i = 0; i < 4; i++)
#pragma unroll
                for (int j = 0; j < 4; j++)
                    acc[i][j] = __builtin_amdgcn_mfma_f32_16x16x32_f16(af[i], bfv[j], acc[i][j], 0, 0, 0);
        }
    }

    // epilogue: scatter into q [B,H,L,D] (pre-scaled), k [B,H,L,D], v^T [B,H,D,L]
    const int mbase = tm * 128, nbase = tn * 128;
#pragma unroll
    for (int j = 0; j < 4; j++) {
        int n = nbase + wn + j * 16 + l16;
        float bias = qkv_b[n];
        int s = n / 384, rem = n % 384;
        int h = rem >> 5, d = rem & 31;
#pragma unroll
        for (int i = 0; i < 4; i++) {
#pragma unroll
            for (int r = 0; r < 4; r++) {
                int m = mbase + wm + i * 16 + quad * 4 + r;
                int b = m / 49, l = m - b * 49;
                float v = acc[i][j][r] + bias;
                size_t bh = (size_t)b * NH + h;
                if (s == 0)       qo[(bh * 49 + l) * 32 + d] = (_Float16)(v * SCALE);
                else if (s == 1)  ko[(bh * 49 + l) * 32 + d] = (_Float16)v;
                else              vo[(bh * 32 + d) * 49 + l] = (_Float16)v;
            }
        }
    }
}

// ---------------- attention: one block per (b,h), 4 waves ----------------

__global__ __launch_bounds__(256) void attn_kernel(const _Float16* __restrict__ qg,
                                                   const _Float16* __restrict__ kg,
                                                   const _Float16* __restrict__ vg,
                                                   const int* __restrict__ rel_index,
                                                   const float* __restrict__ rel_table,
                                                   const float* __restrict__ mask,
                                                   _Float16* __restrict__ out) {
    const int h = blockIdx.x, b = blockIdx.y;
    const int t = threadIdx.x;
    const int wave = t >> 6, lane = t & 63, quad = lane >> 4, l16 = lane & 15;

    __shared__ float sc[64 * 66];       // scores, stride 66 (2-way-free for row scans)
    __shared__ _Float16 P[64 * 72];     // probs, stride 72 (144B rows)
    __shared__ _Float16 Vs[32 * 72];    // V^T staged, cols 49..63 zeroed
    __shared__ float rsum[64];

    const size_t bh = (size_t)b * NH + h;
    const _Float16* qb = qg + bh * 49 * 32;
    const _Float16* kb = kg + bh * 49 * 32;
    const _Float16* vb = vg + bh * 32 * 49;

    // stage V^T with zero padding (k=49..63 must be 0 for PV)
    for (int i = t; i < 32 * 64; i += 256) {
        int d = i >> 6, l = i & 63;
        Vs[d * 72 + l] = (l < 49) ? vb[d * 49 + l] : (_Float16)0.f;
    }

    // QK^T: wave handles m-tile `wave`; fragments straight from global (coalesced 1KB/wave)
    int qrow = wave * 16 + l16; if (qrow > 48) qrow = 48;
    half8 aq = *(const half8*)(qb + qrow * 32 + quad * 8);
    f32x4 s_acc[4];
#pragma unroll
    for (int j = 0; j < 4; j++) {
        int krow = j * 16 + l16; if (krow > 48) krow = 48;
        half8 bk = *(const half8*)(kb + krow * 32 + quad * 8);
        f32x4 z = {0.f, 0.f, 0.f, 0.f};
        s_acc[j] = __builtin_amdgcn_mfma_f32_16x16x32_f16(aq, bk, z, 0, 0, 0);
    }
#pragma unroll
    for (int j = 0; j < 4; j++)
#pragma unroll
        for (int r = 0; r < 4; r++)
            sc[(wave * 16 + quad * 4 + r) * 66 + j * 16 + l16] = s_acc[j][r];
    __syncthreads();

    // softmax per row (rows are thread-private; unnormalized exp, 1/sum deferred)
    if (t < 49) {
        const int* ri = rel_index + t * 49;
        const float* mrow = mask + ((size_t)(b & 63) * 49 + t) * 49;
        float mx = -1e30f;
        for (int j = 0; j < 49; j++) {
            float x = sc[t * 66 + j] + rel_table[ri[j] * NH + h] + mrow[j];
            sc[t * 66 + j] = x;
            mx = fmaxf(mx, x);
        }
        float sum = 0.f;
        for (int j = 0; j < 49; j++) {
            float e = __expf(sc[t * 66 + j] - mx);
            sum += e;
            P[t * 72 + j] = (_Float16)e;
        }
        for (int j = 49; j < 64; j++) P[t * 72 + j] = (_Float16)0.f;
        rsum[t] = 1.f / sum;
    }
    __syncthreads();

    // PV: wave handles m-tile `wave`; out[b, q, h, d]
    f32x4 oacc[2] = {};
#pragma unroll
    for (int ks = 0; ks < 2; ks++) {
        half8 ap = *(const half8*)(&P[(wave * 16 + l16) * 72 + ks * 32 + quad * 8]);
#pragma unroll
        for (int nt = 0; nt < 2; nt++) {
            half8 bv = *(const half8*)(&Vs[(nt * 16 + l16) * 72 + ks * 32 + quad * 8]);
            oacc[nt] = __builtin_amdgcn_mfma_f32_16x16x32_f16(ap, bv, oacc[nt], 0, 0, 0);
        }
    }
#pragma unroll
    for (int nt = 0; nt < 2; nt++) {
#pragma unroll
        for (int r = 0; r < 4; r++) {
            int row = wave * 16 + quad * 4 + r;
            if (row < 49) {
                int d = nt * 16 + l16;
                float val = oacc[nt][r] * rsum[row];
                out[((size_t)b * 49 + row) * 384 + h * 32 + d] = (_Float16)val;
            }
        }
    }
}

// ---------------- proj GEMM: [100352,384] x [384,384] + bias -> f32 out ----------------

__global__ __launch_bounds__(256) void gemm_proj(const _Float16* __restrict__ A,
                                                 const _Float16* __restrict__ Bt,
                                                 const float* __restrict__ proj_b,
                                                 float* __restrict__ out) {
    __shared__ _Float16 As[128 * SA];
    __shared__ _Float16 Bs[128 * SA];
    const int K = 384;
    const int tn = blockIdx.x, tm = blockIdx.y;
    const int t = threadIdx.x;
    const int wave = t >> 6, lane = t & 63;
    const int wm = (wave & 1) * 64, wn = (wave >> 1) * 64;
    const int quad = lane >> 4, l16 = lane & 15;

    f32x4 acc[4][4] = {};

    const _Float16* Abase = A + (size_t)(tm * 128) * K;
    const _Float16* Bbase = Bt + (size_t)(tn * 128) * K;

    for (int k0 = 0; k0 < K; k0 += 64) {
        __syncthreads();
#pragma unroll
        for (int i = 0; i < 4; i++) {
            int c = t + 256 * i;
            int row = c >> 3, cc = (c & 7) * 8;
            uint4 av = *(const uint4*)(Abase + (size_t)row * K + k0 + cc);
            *(uint4*)(&As[row * SA + cc]) = av;
            uint4 bv = *(const uint4*)(Bbase + (size_t)row * K + k0 + cc);
            *(uint4*)(&Bs[row * SA + cc]) = bv;
        }
        __syncthreads();
#pragma unroll
        for (int ks = 0; ks < 2; ks++) {
            half8 af[4], bfv[4];
#pragma unroll
            for (int i = 0; i < 4; i++)
                af[i] = *(const half8*)(&As[(wm + i * 16 + l16) * SA + ks * 32 + quad * 8]);
#pragma unroll
            for (int j = 0; j < 4; j++)
                bfv[j] = *(const half8*)(&Bs[(wn + j * 16 + l16) * SA + ks * 32 + quad * 8]);
#pragma unroll
            for (int i = 0; i < 4; i++)
#pragma unroll
                for (int j = 0; j < 4; j++)
                    acc[i][j] = __builtin_amdgcn_mfma_f32_16x16x32_f16(af[i], bfv[j], acc[i][j], 0, 0, 0);
        }
    }

    const int mbase = tm * 128, nbase = tn * 128;
#pragma unroll
    for (int j = 0; j < 4; j++) {
        int n = nbase + wn + j * 16 + l16;
        float bias = proj_b[n];
#pragma unroll
        for (int i = 0; i < 4; i++) {
#pragma unroll
            for (int r = 0; r < 4; r++) {
                int m = mbase + wm + i * 16 + quad * 4 + r;
                out[(size_t)m * 384 + n] = acc[i][j][r] + bias;
            }
        }
    }
}

// ---------------- launch ----------------

extern "C" void kernel_launch(void* const* d_in, const int* in_sizes, int n_in,
                              void* d_out, int out_size, void* d_ws, size_t ws_size,
                              hipStream_t stream) {
    const float* x        = (const float*)d_in[0];
    const int*   rel_idx  = (const int*)d_in[1];
    const float* amask    = (const float*)d_in[2];
    const float* qkv_w    = (const float*)d_in[3];
    const float* qkv_b    = (const float*)d_in[4];
    const float* rtable   = (const float*)d_in[5];
    const float* proj_w   = (const float*)d_in[6];
    const float* proj_b   = (const float*)d_in[7];
    float* out = (float*)d_out;

    char* w = (char*)d_ws;
    const size_t XB = (size_t)MM * CDIM * 2;   // 77,070,336
    _Float16* x_h    = (_Float16*)w;
    _Float16* wqkvT  = (_Float16*)(w + XB);
    _Float16* wprojT = (_Float16*)(w + XB + 884736);
    _Float16* q_h    = (_Float16*)(w + XB + 884736 + 294912);
    _Float16* k_h    = (_Float16*)(w + 2 * XB + 884736 + 294912);
    _Float16* v_h    = (_Float16*)(w + 3 * XB + 884736 + 294912);
    _Float16* ao_h   = x_h;  // alias: x_h dead after gemm_qkv

    int nx = MM * CDIM;  // 38,535,168
    convert_x<<<nx / 1024, 256, 0, stream>>>(x, x_h, nx);
    convert_w<<<(1152 * 384 + 384 * 384) / 256, 256, 0, stream>>>(qkv_w, proj_w, wqkvT, wprojT);
    gemm_qkv<<<dim3(9, MM / 128), 256, 0, stream>>>(x_h, wqkvT, qkv_b, q_h, k_h, v_h);
    attn_kernel<<<dim3(NH, NB), 256, 0, stream>>>(q_h, k_h, v_h, rel_idx, rtable, amask, ao_h);
    gemm_proj<<<dim3(3, MM / 128), 256, 0, stream>>>(ao_h, wprojT, proj_b, out);
}

// Round 2
// 705.415 us; speedup vs baseline: 1.1289x; 1.1289x over previous
//
#include <hip/hip_runtime.h>

typedef _Float16 half8 __attribute__((ext_vector_type(8)));
typedef _Float16 half4v __attribute__((ext_vector_type(4)));
typedef float f32x4 __attribute__((ext_vector_type(4)));
typedef float f32x2 __attribute__((ext_vector_type(2)));

constexpr int NB = 2048;        // windows (batch)
constexpr int CDIM = 384;       // channels
constexpr int NH = 12;          // heads
constexpr int MM = NB * 49;     // 100352 rows
constexpr float SCALE = 0.17677669529663687f;  // 1/sqrt(32)

// async global->LDS, 16B per lane; lds ptr must be wave-uniform (HW adds lane*16)
__device__ __forceinline__ void async16(const void* g, void* l) {
    __builtin_amdgcn_global_load_lds((const __attribute__((address_space(1))) void*)g,
                                     (__attribute__((address_space(3))) void*)l, 16, 0, 0);
}

// ---------------- convert kernels ----------------

__global__ __launch_bounds__(256) void convert_x(const float* __restrict__ x,
                                                 _Float16* __restrict__ o, int n) {
    int i = (blockIdx.x * 256 + threadIdx.x) * 4;
    if (i < n) {
        float4 v = *(const float4*)(x + i);
        half4v h = { (_Float16)v.x, (_Float16)v.y, (_Float16)v.z, (_Float16)v.w };
        *(half4v*)(o + i) = h;
    }
}

__global__ __launch_bounds__(256) void convert_w(const float* __restrict__ qkv_w,
                                                 const float* __restrict__ proj_w,
                                                 _Float16* __restrict__ qkvT,
                                                 _Float16* __restrict__ projT) {
    int i = blockIdx.x * 256 + threadIdx.x;
    if (i < 1152 * 384) {
        int n = i / 384, kk = i % 384;
        qkvT[i] = (_Float16)qkv_w[kk * 1152 + n];
    } else {
        int j = i - 1152 * 384;
        if (j < 384 * 384) {
            int n = j / 384, kk = j % 384;
            projT[j] = (_Float16)proj_w[kk * 384 + n];
        }
    }
}

// ---------------- fused bias+mask table: FT[w][h][k][q], 64 rows x 64 cols f32 ----------------
// FT[(w*12+h)*4096 + k*64 + q] = rel_bias[h][q][k] + mask[w][q][k]; 0 outside 49x49.
// Transposed (k-major) so attn acc-init reads are f32x4 over q.

__global__ __launch_bounds__(256) void build_ft(const int* __restrict__ rel_index,
                                                const float* __restrict__ rtable,
                                                const float* __restrict__ mask,
                                                float* __restrict__ FT) {
    int wh = blockIdx.x;            // 0..767
    int w = wh / 12, h = wh - w * 12;
    float* dst = FT + (size_t)wh * 4096;
    for (int idx = threadIdx.x; idx < 4096; idx += 256) {
        int k = idx >> 6, q = idx & 63;
        float v = 0.f;
        if (k < 49 && q < 49)
            v = rtable[rel_index[q * 49 + k] * NH + h] + mask[(size_t)w * 2401 + q * 49 + k];
        dst[idx] = v;
    }
}

// ---------------- QKV GEMM: [100352,384] x [384,1152], global_load_lds + xor swizzle ----------------
// LDS row-major [128][64] halves, no pad. LDS chunk-slot s of row r holds global chunk s^(r&7).

__global__ __launch_bounds__(256) void gemm_qkv(const _Float16* __restrict__ A,
                                                const _Float16* __restrict__ Bt,
                                                const float* __restrict__ qkv_b,
                                                _Float16* __restrict__ qo,
                                                _Float16* __restrict__ ko,
                                                _Float16* __restrict__ vo) {
    __shared__ _Float16 As[128 * 64];
    __shared__ _Float16 Bs[128 * 64];
    const int K = 384;
    const int tn = blockIdx.x, tm = blockIdx.y;
    const int t = threadIdx.x;
    const int wave = t >> 6, lane = t & 63;
    const int wm = (wave & 1) * 64, wn = (wave >> 1) * 64;
    const int quad = lane >> 4, l16 = lane & 15;
    const int rsub = lane >> 3, p = lane & 7;

    f32x4 acc[4][4] = {};
    const _Float16* Abase = A + (size_t)(tm * 128) * K;
    const _Float16* Bbase = Bt + (size_t)(tn * 128) * K;

    for (int k0 = 0; k0 < K; k0 += 64) {
        __syncthreads();
#pragma unroll
        for (int n = 0; n < 4; n++) {
            int ni = wave * 4 + n;
            int row = ni * 8 + rsub;
            int chunk = p ^ (row & 7);
            async16(Abase + (size_t)row * K + k0 + chunk * 8, (char*)As + ni * 1024);
            async16(Bbase + (size_t)row * K + k0 + chunk * 8, (char*)Bs + ni * 1024);
        }
        __syncthreads();
#pragma unroll
        for (int ks = 0; ks < 2; ks++) {
            half8 af[4], bfv[4];
#pragma unroll
            for (int i = 0; i < 4; i++)
                af[i] = *(const half8*)(&As[(wm + i * 16 + l16) * 64 + (((ks * 4 + quad) ^ (l16 & 7)) * 8)]);
#pragma unroll
            for (int j = 0; j < 4; j++)
                bfv[j] = *(const half8*)(&Bs[(wn + j * 16 + l16) * 64 + (((ks * 4 + quad) ^ (l16 & 7)) * 8)]);
#pragma unroll
            for (int i = 0; i < 4; i++)
#pragma unroll
                for (int j = 0; j < 4; j++)
                    acc[i][j] = __builtin_amdgcn_mfma_f32_16x16x32_f16(af[i], bfv[j], acc[i][j], 0, 0, 0);
        }
    }

    // epilogue: q [B,H,49,32] (pre-scaled), k [B,H,49,32], v^T [B,H,32,64] (l-pad uninit, P cols>=49 are 0)
    const int mbase = tm * 128, nbase = tn * 128;
#pragma unroll
    for (int j = 0; j < 4; j++) {
        int n = nbase + wn + j * 16 + l16;
        float bias = qkv_b[n];
        int s = n / 384, rem = n % 384;
        int h = rem >> 5, d = rem & 31;
#pragma unroll
        for (int i = 0; i < 4; i++) {
#pragma unroll
            for (int r = 0; r < 4; r++) {
                int m = mbase + wm + i * 16 + quad * 4 + r;
                int b = m / 49, l = m - b * 49;
                float v = acc[i][j][r] + bias;
                size_t bh = (size_t)b * NH + h;
                if (s == 0)       qo[(bh * 49 + l) * 32 + d] = (_Float16)(v * SCALE);
                else if (s == 1)  ko[(bh * 49 + l) * 32 + d] = (_Float16)v;
                else              vo[(bh * 32 + d) * 64 + l] = (_Float16)v;
            }
        }
    }
}

// ---------------- attention: one WAVE per (b,h), registers-only softmax ----------------

__global__ __launch_bounds__(256) void attn_kernel(const _Float16* __restrict__ qg,
                                                   const _Float16* __restrict__ kg,
                                                   const _Float16* __restrict__ vg,
                                                   const float* __restrict__ FT,
                                                   _Float16* __restrict__ out) {
    __shared__ float Pb[2][4][16 * 66];   // [parity][wave][16 rows x stride 66]
    const int t = threadIdx.x;
    const int wave = t >> 6, lane = t & 63, quad = lane >> 4, l16 = lane & 15;
    const int gw = blockIdx.x * 4 + wave;           // global (b,h), 0..24575
    const int b = gw / 12, h = gw - b * 12;

    const _Float16* qb = qg + (size_t)gw * 49 * 32;
    const _Float16* kb = kg + (size_t)gw * 49 * 32;
    const _Float16* vb = vg + (size_t)gw * 32 * 64;
    const float* Fb = FT + ((size_t)((b & 63) * 12 + h)) * 4096;

    // K fragments (rows clamped; k>=49 masked later) and V^T B-fragments, straight from global
    half8 bk[4], bv[2][2];
#pragma unroll
    for (int j = 0; j < 4; j++) {
        int krow = j * 16 + l16; if (krow > 48) krow = 48;
        bk[j] = *(const half8*)(kb + krow * 32 + quad * 8);
    }
#pragma unroll
    for (int nt = 0; nt < 2; nt++)
#pragma unroll
        for (int ks = 0; ks < 2; ks++)
            bv[nt][ks] = *(const half8*)(vb + (nt * 16 + l16) * 64 + ks * 32 + quad * 8);

#pragma unroll
    for (int i = 0; i < 4; i++) {
        int qrow = i * 16 + l16; if (qrow > 48) qrow = 48;
        half8 aq = *(const half8*)(qb + qrow * 32 + quad * 8);

        // acc init = fused bias+mask (C layout: row q = quad*4+r, col k = j*16+l16)
        f32x4 acc[4];
#pragma unroll
        for (int j = 0; j < 4; j++)
            acc[j] = *(const f32x4*)(Fb + (j * 16 + l16) * 64 + i * 16 + quad * 4);
#pragma unroll
        for (int j = 0; j < 4; j++)
            acc[j] = __builtin_amdgcn_mfma_f32_16x16x32_f16(aq, bk[j], acc[j], 0, 0, 0);

        // mask k = 48+l16 > 48
        if (l16 != 0) {
#pragma unroll
            for (int r = 0; r < 4; r++) acc[3][r] = -1e30f;
        }

        // softmax in registers; row owner = (quad, r), reduce across 16 lanes of quad
        float rinv[4];
#pragma unroll
        for (int r = 0; r < 4; r++) {
            float m = fmaxf(fmaxf(acc[0][r], acc[1][r]), fmaxf(acc[2][r], acc[3][r]));
            m = fmaxf(m, __shfl_xor(m, 1, 64));
            m = fmaxf(m, __shfl_xor(m, 2, 64));
            m = fmaxf(m, __shfl_xor(m, 4, 64));
            m = fmaxf(m, __shfl_xor(m, 8, 64));
            float s = 0.f;
#pragma unroll
            for (int j = 0; j < 4; j++) {
                float e = __expf(acc[j][r] - m);   // masked -> exp(-inf) = 0
                acc[j][r] = e;
                s += e;
            }
            s += __shfl_xor(s, 1, 64);
            s += __shfl_xor(s, 2, 64);
            s += __shfl_xor(s, 4, 64);
            s += __shfl_xor(s, 8, 64);
            rinv[r] = 1.f / s;
        }

        // C-layout -> A-layout round trip through per-wave LDS (stride 66: 2-way banks both sides)
        float* Pw = &Pb[i & 1][wave][0];
#pragma unroll
        for (int j = 0; j < 4; j++)
#pragma unroll
            for (int r = 0; r < 4; r++)
                Pw[(quad * 4 + r) * 66 + j * 16 + l16] = acc[j][r];
        __syncthreads();

        f32x4 oacc[2] = {};
#pragma unroll
        for (int ks = 0; ks < 2; ks++) {
            const float* pp = Pw + l16 * 66 + ks * 32 + quad * 8;
            f32x2 p0 = *(const f32x2*)(pp);
            f32x2 p1 = *(const f32x2*)(pp + 2);
            f32x2 p2 = *(const f32x2*)(pp + 4);
            f32x2 p3 = *(const f32x2*)(pp + 6);
            half8 ap = { (_Float16)p0.x, (_Float16)p0.y, (_Float16)p1.x, (_Float16)p1.y,
                         (_Float16)p2.x, (_Float16)p2.y, (_Float16)p3.x, (_Float16)p3.y };
#pragma unroll
            for (int nt = 0; nt < 2; nt++)
                oacc[nt] = __builtin_amdgcn_mfma_f32_16x16x32_f16(ap, bv[nt][ks], oacc[nt], 0, 0, 0);
        }

        // epilogue: out[b, q, h*32+d] fp16
#pragma unroll
        for (int nt = 0; nt < 2; nt++)
#pragma unroll
            for (int r = 0; r < 4; r++) {
                int q = i * 16 + quad * 4 + r;
                if (q < 49)
                    out[((size_t)b * 49 + q) * 384 + h * 32 + nt * 16 + l16] =
                        (_Float16)(oacc[nt][r] * rinv[r]);
            }
    }
}

// ---------------- proj GEMM: [100352,384] x [384,384] + bias -> f32 out ----------------

__global__ __launch_bounds__(256) void gemm_proj(const _Float16* __restrict__ A,
                                                 const _Float16* __restrict__ Bt,
                                                 const float* __restrict__ proj_b,
                                                 float* __restrict__ out) {
    __shared__ _Float16 As[128 * 64];
    __shared__ _Float16 Bs[128 * 64];
    const int K = 384;
    const int tn = blockIdx.x, tm = blockIdx.y;
    const int t = threadIdx.x;
    const int wave = t >> 6, lane = t & 63;
    const int wm = (wave & 1) * 64, wn = (wave >> 1) * 64;
    const int quad = lane >> 4, l16 = lane & 15;
    const int rsub = lane >> 3, p = lane & 7;

    f32x4 acc[4][4] = {};
    const _Float16* Abase = A + (size_t)(tm * 128) * K;
    const _Float16* Bbase = Bt + (size_t)(tn * 128) * K;

    for (int k0 = 0; k0 < K; k0 += 64) {
        __syncthreads();
#pragma unroll
        for (int n = 0; n < 4; n++) {
            int ni = wave * 4 + n;
            int row = ni * 8 + rsub;
            int chunk = p ^ (row & 7);
            async16(Abase + (size_t)row * K + k0 + chunk * 8, (char*)As + ni * 1024);
            async16(Bbase + (size_t)row * K + k0 + chunk * 8, (char*)Bs + ni * 1024);
        }
        __syncthreads();
#pragma unroll
        for (int ks = 0; ks < 2; ks++) {
            half8 af[4], bfv[4];
#pragma unroll
            for (int i = 0; i < 4; i++)
                af[i] = *(const half8*)(&As[(wm + i * 16 + l16) * 64 + (((ks * 4 + quad) ^ (l16 & 7)) * 8)]);
#pragma unroll
            for (int j = 0; j < 4; j++)
                bfv[j] = *(const half8*)(&Bs[(wn + j * 16 + l16) * 64 + (((ks * 4 + quad) ^ (l16 & 7)) * 8)]);
#pragma unroll
            for (int i = 0; i < 4; i++)
#pragma unroll
                for (int j = 0; j < 4; j++)
                    acc[i][j] = __builtin_amdgcn_mfma_f32_16x16x32_f16(af[i], bfv[j], acc[i][j], 0, 0, 0);
        }
    }

    const int mbase = tm * 128, nbase = tn * 128;
#pragma unroll
    for (int j = 0; j < 4; j++) {
        int n = nbase + wn + j * 16 + l16;
        float bias = proj_b[n];
#pragma unroll
        for (int i = 0; i < 4; i++) {
#pragma unroll
            for (int r = 0; r < 4; r++) {
                int m = mbase + wm + i * 16 + quad * 4 + r;
                out[(size_t)m * 384 + n] = acc[i][j][r] + bias;
            }
        }
    }
}

// ---------------- launch ----------------

extern "C" void kernel_launch(void* const* d_in, const int* in_sizes, int n_in,
                              void* d_out, int out_size, void* d_ws, size_t ws_size,
                              hipStream_t stream) {
    const float* x        = (const float*)d_in[0];
    const int*   rel_idx  = (const int*)d_in[1];
    const float* amask    = (const float*)d_in[2];
    const float* qkv_w    = (const float*)d_in[3];
    const float* qkv_b    = (const float*)d_in[4];
    const float* rtable   = (const float*)d_in[5];
    const float* proj_w   = (const float*)d_in[6];
    const float* proj_b   = (const float*)d_in[7];
    float* out = (float*)d_out;

    char* w = (char*)d_ws;
    const size_t XB = (size_t)MM * CDIM * 2;       // 77,070,336
    const size_t VB = (size_t)NB * NH * 32 * 64 * 2; // 100,663,296 (v^T stride-64)
    _Float16* x_h    = (_Float16*)w;
    _Float16* wqkvT  = (_Float16*)(w + XB);
    _Float16* wprojT = (_Float16*)(w + XB + 884736);
    char* base0 = w + XB + 884736 + 294912;
    _Float16* q_h = (_Float16*)(base0);
    _Float16* k_h = (_Float16*)(base0 + XB);
    _Float16* v_h = (_Float16*)(base0 + 2 * XB);
    float*    FT  = (float*)(base0 + 2 * XB + VB);  // 768*4096*4 = 12,582,912
    _Float16* ao_h = x_h;  // alias: x_h dead after gemm_qkv

    int nx = MM * CDIM;
    convert_x<<<nx / 1024, 256, 0, stream>>>(x, x_h, nx);
    convert_w<<<(1152 * 384 + 384 * 384) / 256, 256, 0, stream>>>(qkv_w, proj_w, wqkvT, wprojT);
    build_ft<<<768, 256, 0, stream>>>(rel_idx, rtable, amask, FT);
    gemm_qkv<<<dim3(9, MM / 128), 256, 0, stream>>>(x_h, wqkvT, qkv_b, q_h, k_h, v_h);
    attn_kernel<<<NB * NH / 4, 256, 0, stream>>>(q_h, k_h, v_h, FT, ao_h);
    gemm_proj<<<dim3(3, MM / 128), 256, 0, stream>>>(ao_h, wprojT, proj_b, out);
}

// Round 3
// 626.921 us; speedup vs baseline: 1.2702x; 1.1252x over previous
//
#include <hip/hip_runtime.h>

typedef _Float16 half8 __attribute__((ext_vector_type(8)));
typedef float f32x4 __attribute__((ext_vector_type(4)));

constexpr int NB = 2048;        // windows (batch)
constexpr int CDIM = 384;       // channels
constexpr int NH = 12;          // heads
constexpr int MM = NB * 49;     // 100352 rows
constexpr int NTOT = 1152;      // qkv output cols
constexpr float SCALE = 0.17677669529663687f;  // 1/sqrt(32)

constexpr int XBLK = 37632;     // MM*CDIM/1024
constexpr int WBLK = 2304;      // (1152*384+384*384)/256

// async global->LDS, 16B per lane; lds ptr wave-uniform (HW adds lane*16)
__device__ __forceinline__ void async16(const void* g, void* l) {
    __builtin_amdgcn_global_load_lds((const __attribute__((address_space(1))) void*)g,
                                     (__attribute__((address_space(3))) void*)l, 16, 0, 0);
}

// ---------------- fused prep: convert x, transpose weights, build bias+mask table ----------------
// FT[w][h][k][q] (64x64 f32): rel_bias[h][q][k] + mask[w][q][k]; 0 outside 49x49.

__global__ __launch_bounds__(256) void prep(const float* __restrict__ x,
                                            const float* __restrict__ qkv_w,
                                            const float* __restrict__ proj_w,
                                            const int* __restrict__ rel_index,
                                            const float* __restrict__ rtable,
                                            const float* __restrict__ mask,
                                            _Float16* __restrict__ x_h,
                                            _Float16* __restrict__ qkvT,
                                            _Float16* __restrict__ projT,
                                            float* __restrict__ FT) {
    int bid = blockIdx.x;
    if (bid < XBLK) {
        size_t i = ((size_t)bid * 256 + threadIdx.x) * 4;
        float4 v = *(const float4*)(x + i);
        _Float16 h0 = (_Float16)v.x, h1 = (_Float16)v.y, h2 = (_Float16)v.z, h3 = (_Float16)v.w;
        _Float16* o = x_h + i;
        o[0] = h0; o[1] = h1; o[2] = h2; o[3] = h3;
    } else if (bid < XBLK + WBLK) {
        int i = (bid - XBLK) * 256 + threadIdx.x;
        if (i < 1152 * 384) {
            int n = i / 384, kk = i % 384;
            qkvT[i] = (_Float16)qkv_w[kk * 1152 + n];
        } else {
            int j = i - 1152 * 384;
            int n = j / 384, kk = j % 384;
            projT[j] = (_Float16)proj_w[kk * 384 + n];
        }
    } else {
        int wh = bid - XBLK - WBLK;     // 0..767
        int w = wh / 12, h = wh - w * 12;
        float* dst = FT + (size_t)wh * 4096;
        for (int idx = threadIdx.x; idx < 4096; idx += 256) {
            int k = idx >> 6, q = idx & 63;
            float v = 0.f;
            if (k < 49 && q < 49)
                v = rtable[rel_index[q * 49 + k] * NH + h] + mask[(size_t)w * 2401 + q * 49 + k];
            dst[idx] = v;
        }
    }
}

// ---------------- QKV GEMM: [100352,384] x [384,1152] -> C[100352][1152] f16 ----------------
// K-loop: global_load_lds(16B) + xor-swizzled LDS. Epilogue: LDS transpose + 256B-coalesced stores.

__global__ __launch_bounds__(256) void gemm_qkv(const _Float16* __restrict__ A,
                                                const _Float16* __restrict__ Bt,
                                                const float* __restrict__ qkv_b,
                                                _Float16* __restrict__ C) {
    __shared__ union {
        struct { _Float16 A[128 * 64]; _Float16 B[128 * 64]; } st;
        _Float16 tile[128 * 136];
    } sm;
    _Float16* As = sm.st.A;
    _Float16* Bs = sm.st.B;

    const int K = 384;
    const int tn = blockIdx.x, tm = blockIdx.y;
    const int t = threadIdx.x;
    const int wave = t >> 6, lane = t & 63;
    const int wm = (wave & 1) * 64, wn = (wave >> 1) * 64;
    const int quad = lane >> 4, l16 = lane & 15;
    const int rsub = lane >> 3, p = lane & 7;

    f32x4 acc[4][4] = {};
    const _Float16* Abase = A + (size_t)(tm * 128) * K;
    const _Float16* Bbase = Bt + (size_t)(tn * 128) * K;

    for (int k0 = 0; k0 < K; k0 += 64) {
        __syncthreads();
#pragma unroll
        for (int n = 0; n < 4; n++) {
            int ni = wave * 4 + n;
            int row = ni * 8 + rsub;
            int chunk = p ^ (row & 7);
            async16(Abase + (size_t)row * K + k0 + chunk * 8, (char*)As + ni * 1024);
            async16(Bbase + (size_t)row * K + k0 + chunk * 8, (char*)Bs + ni * 1024);
        }
        __syncthreads();
#pragma unroll
        for (int ks = 0; ks < 2; ks++) {
            half8 af[4], bfv[4];
#pragma unroll
            for (int i = 0; i < 4; i++)
                af[i] = *(const half8*)(&As[(wm + i * 16 + l16) * 64 + (((ks * 4 + quad) ^ (l16 & 7)) * 8)]);
#pragma unroll
            for (int j = 0; j < 4; j++)
                bfv[j] = *(const half8*)(&Bs[(wn + j * 16 + l16) * 64 + (((ks * 4 + quad) ^ (l16 & 7)) * 8)]);
#pragma unroll
            for (int i = 0; i < 4; i++)
#pragma unroll
                for (int j = 0; j < 4; j++)
                    acc[i][j] = __builtin_amdgcn_mfma_f32_16x16x32_f16(af[i], bfv[j], acc[i][j], 0, 0, 0);
        }
    }

    // ---- epilogue: bias (+q-scale) -> f16 LDS tile (stride 136) -> coalesced 16B/lane stores
    __syncthreads();                       // all LDS frag reads done before overwrite
    const int nbase = tn * 128, mbase = tm * 128;
    const float s = (tn < 3) ? SCALE : 1.f;
    float bj[4];
#pragma unroll
    for (int j = 0; j < 4; j++) bj[j] = qkv_b[nbase + wn + j * 16 + l16];

#pragma unroll
    for (int j = 0; j < 4; j++) {
        int n = wn + j * 16 + l16;
#pragma unroll
        for (int i = 0; i < 4; i++) {
#pragma unroll
            for (int r = 0; r < 4; r++) {
                int m = wm + i * 16 + quad * 4 + r;
                sm.tile[m * 136 + n] = (_Float16)((acc[i][j][r] + bj[j]) * s);
            }
        }
    }
    __syncthreads();

    const int rcol = (t & 15) * 8;
    const int rrow0 = t >> 4;
#pragma unroll
    for (int g = 0; g < 8; g++) {
        int row = g * 16 + rrow0;
        half8 val = *(const half8*)(&sm.tile[row * 136 + rcol]);
        *(half8*)(C + (size_t)(mbase + row) * NTOT + nbase + rcol) = val;
    }
}

// ---------------- attention: one WAVE per (b,h); no barriers ----------------

__global__ __launch_bounds__(256) void attn_kernel(const _Float16* __restrict__ C,
                                                   const float* __restrict__ FT,
                                                   _Float16* __restrict__ out) {
    __shared__ _Float16 Vt[4][32 * 72];   // per-wave V^T [d][l], l padded to 64 (zeros)
    __shared__ _Float16 Pb[4][16 * 72];   // per-wave P tile (f16)
    const int t = threadIdx.x;
    const int wave = t >> 6, lane = t & 63, quad = lane >> 4, l16 = lane & 15;
    const int gw = blockIdx.x * 4 + wave;           // global (b,h)
    const int b = gw / 12, h = gw - b * 12;

    const _Float16* qb = C + (size_t)b * 49 * NTOT + h * 32;
    const _Float16* kb = qb + 384;
    const _Float16* vb = qb + 768;
    const float* Fb = FT + ((size_t)((b & 63) * 12 + h)) * 4096;

    _Float16* vt = Vt[wave];
    // zero rows l=48..63 (one b128/wave), then stage V^T rows 0..48
    {
        int d = lane >> 1, seg = lane & 1;
        half8 z = {};
        *(half8*)(&vt[d * 72 + 48 + seg * 8]) = z;
    }
#pragma unroll
    for (int i2 = 0; i2 < 4; i2++) {
        int l = i2 * 16 + (lane >> 2);
        int d0 = (lane & 3) * 8;
        if (l < 49) {
            half8 v8 = *(const half8*)(vb + (size_t)l * NTOT + d0);
#pragma unroll
            for (int e = 0; e < 8; e++)
                vt[(d0 + e) * 72 + l] = v8[e];
        }
    }

    half8 bk[4];
#pragma unroll
    for (int j = 0; j < 4; j++) {
        int krow = j * 16 + l16; if (krow > 48) krow = 48;
        bk[j] = *(const half8*)(kb + (size_t)krow * NTOT + quad * 8);
    }
    half8 bv[2][2];
#pragma unroll
    for (int nt = 0; nt < 2; nt++)
#pragma unroll
        for (int ks = 0; ks < 2; ks++)
            bv[nt][ks] = *(const half8*)(&vt[(nt * 16 + l16) * 72 + ks * 32 + quad * 8]);

    _Float16* Pw = Pb[wave];
#pragma unroll
    for (int i = 0; i < 4; i++) {
        int qrow = i * 16 + l16; if (qrow > 48) qrow = 48;
        half8 aq = *(const half8*)(qb + (size_t)qrow * NTOT + quad * 8);

        f32x4 acc[4];
#pragma unroll
        for (int j = 0; j < 4; j++)
            acc[j] = *(const f32x4*)(Fb + (j * 16 + l16) * 64 + i * 16 + quad * 4);
#pragma unroll
        for (int j = 0; j < 4; j++)
            acc[j] = __builtin_amdgcn_mfma_f32_16x16x32_f16(aq, bk[j], acc[j], 0, 0, 0);

        if (l16 != 0) {                   // mask k = 48+l16 > 48
#pragma unroll
            for (int r = 0; r < 4; r++) acc[3][r] = -1e30f;
        }

        float rinv[4];
#pragma unroll
        for (int r = 0; r < 4; r++) {
            float m = fmaxf(fmaxf(acc[0][r], acc[1][r]), fmaxf(acc[2][r], acc[3][r]));
            m = fmaxf(m, __shfl_xor(m, 1, 64));
            m = fmaxf(m, __shfl_xor(m, 2, 64));
            m = fmaxf(m, __shfl_xor(m, 4, 64));
            m = fmaxf(m, __shfl_xor(m, 8, 64));
            float sum = 0.f;
#pragma unroll
            for (int j = 0; j < 4; j++) {
                float e = __expf(acc[j][r] - m);
                acc[j][r] = e;
                sum += e;
            }
            sum += __shfl_xor(sum, 1, 64);
            sum += __shfl_xor(sum, 2, 64);
            sum += __shfl_xor(sum, 4, 64);
            sum += __shfl_xor(sum, 8, 64);
            rinv[r] = 1.f / sum;
        }

        // C-layout -> A-layout via per-wave LDS (f16, stride 72); no barriers needed
#pragma unroll
        for (int j = 0; j < 4; j++)
#pragma unroll
            for (int r = 0; r < 4; r++)
                Pw[(quad * 4 + r) * 72 + j * 16 + l16] = (_Float16)acc[j][r];

        f32x4 oacc[2] = {};
#pragma unroll
        for (int ks = 0; ks < 2; ks++) {
            half8 ap = *(const half8*)(&Pw[l16 * 72 + ks * 32 + quad * 8]);
#pragma unroll
            for (int nt = 0; nt < 2; nt++)
                oacc[nt] = __builtin_amdgcn_mfma_f32_16x16x32_f16(ap, bv[nt][ks], oacc[nt], 0, 0, 0);
        }

#pragma unroll
        for (int nt = 0; nt < 2; nt++)
#pragma unroll
            for (int r = 0; r < 4; r++) {
                int q = i * 16 + quad * 4 + r;
                if (q < 49)
                    out[((size_t)b * 49 + q) * CDIM + h * 32 + nt * 16 + l16] =
                        (_Float16)(oacc[nt][r] * rinv[r]);
            }
    }
}

// ---------------- proj GEMM: [100352,384] x [384,384] + bias -> f32 out ----------------

__global__ __launch_bounds__(256) void gemm_proj(const _Float16* __restrict__ A,
                                                 const _Float16* __restrict__ Bt,
                                                 const float* __restrict__ proj_b,
                                                 float* __restrict__ out) {
    __shared__ _Float16 As[128 * 64];
    __shared__ _Float16 Bs[128 * 64];
    const int K = 384;
    const int tn = blockIdx.x, tm = blockIdx.y;
    const int t = threadIdx.x;
    const int wave = t >> 6, lane = t & 63;
    const int wm = (wave & 1) * 64, wn = (wave >> 1) * 64;
    const int quad = lane >> 4, l16 = lane & 15;
    const int rsub = lane >> 3, p = lane & 7;

    f32x4 acc[4][4] = {};
    const _Float16* Abase = A + (size_t)(tm * 128) * K;
    const _Float16* Bbase = Bt + (size_t)(tn * 128) * K;

    for (int k0 = 0; k0 < K; k0 += 64) {
        __syncthreads();
#pragma unroll
        for (int n = 0; n < 4; n++) {
            int ni = wave * 4 + n;
            int row = ni * 8 + rsub;
            int chunk = p ^ (row & 7);
            async16(Abase + (size_t)row * K + k0 + chunk * 8, (char*)As + ni * 1024);
            async16(Bbase + (size_t)row * K + k0 + chunk * 8, (char*)Bs + ni * 1024);
        }
        __syncthreads();
#pragma unroll
        for (int ks = 0; ks < 2; ks++) {
            half8 af[4], bfv[4];
#pragma unroll
            for (int i = 0; i < 4; i++)
                af[i] = *(const half8*)(&As[(wm + i * 16 + l16) * 64 + (((ks * 4 + quad) ^ (l16 & 7)) * 8)]);
#pragma unroll
            for (int j = 0; j < 4; j++)
                bfv[j] = *(const half8*)(&Bs[(wn + j * 16 + l16) * 64 + (((ks * 4 + quad) ^ (l16 & 7)) * 8)]);
#pragma unroll
            for (int i = 0; i < 4; i++)
#pragma unroll
                for (int j = 0; j < 4; j++)
                    acc[i][j] = __builtin_amdgcn_mfma_f32_16x16x32_f16(af[i], bfv[j], acc[i][j], 0, 0, 0);
        }
    }

    const int mbase = tm * 128, nbase = tn * 128;
#pragma unroll
    for (int j = 0; j < 4; j++) {
        int n = nbase + wn + j * 16 + l16;
        float bias = proj_b[n];
#pragma unroll
        for (int i = 0; i < 4; i++) {
#pragma unroll
            for (int r = 0; r < 4; r++) {
                int m = mbase + wm + i * 16 + quad * 4 + r;
                out[(size_t)m * CDIM + n] = acc[i][j][r] + bias;
            }
        }
    }
}

// ---------------- launch ----------------

extern "C" void kernel_launch(void* const* d_in, const int* in_sizes, int n_in,
                              void* d_out, int out_size, void* d_ws, size_t ws_size,
                              hipStream_t stream) {
    const float* x        = (const float*)d_in[0];
    const int*   rel_idx  = (const int*)d_in[1];
    const float* amask    = (const float*)d_in[2];
    const float* qkv_w    = (const float*)d_in[3];
    const float* qkv_b    = (const float*)d_in[4];
    const float* rtable   = (const float*)d_in[5];
    const float* proj_w   = (const float*)d_in[6];
    const float* proj_b   = (const float*)d_in[7];
    float* out = (float*)d_out;

    char* w = (char*)d_ws;
    const size_t XB = (size_t)MM * CDIM * 2;        // 77,070,336
    const size_t CB = (size_t)MM * NTOT * 2;        // 231,211,008
    _Float16* x_h    = (_Float16*)w;
    _Float16* wqkvT  = (_Float16*)(w + XB);
    _Float16* wprojT = (_Float16*)(w + XB + 884736);
    _Float16* Cbuf   = (_Float16*)(w + XB + 884736 + 294912);
    float*    FT     = (float*)(w + XB + 884736 + 294912 + CB);   // 12,582,912
    _Float16* ao_h   = x_h;   // alias: x_h dead after gemm_qkv

    prep<<<XBLK + WBLK + 768, 256, 0, stream>>>(x, qkv_w, proj_w, rel_idx, rtable, amask,
                                                x_h, wqkvT, wprojT, FT);
    gemm_qkv<<<dim3(9, MM / 128), 256, 0, stream>>>(x_h, wqkvT, qkv_b, Cbuf);
    attn_kernel<<<NB * NH / 4, 256, 0, stream>>>(Cbuf, FT, ao_h);
    gemm_proj<<<dim3(3, MM / 128), 256, 0, stream>>>(ao_h, wprojT, proj_b, out);
}